// Round 13
// baseline (35.318 us; speedup 1.0000x reference)
//
#include <hip/hip_runtime.h>
#include <math.h>

// DegradedBicycleRollout: b=512, l=64, h=80, state=12.
// R13: phase-split. R11/R12 isolated the limiter: the serial rollout WAVE
// itself (~22us solo, ~35us at 2/CU); memory path fully hidden since R5.
// make_ctl (tanh+2sigmoid+tan/atan polys, ~35 instr + 6 trans / step) is a
// pure function of controls -> moved OFF the chain wave to 4 ctl waves that
// compute chunk c+1's transforms in parallel (4 tasks/thread) into LDS.
// Chain wave/step: 1 LDS ctl read + ~26 VALU + 4 trans + 2 LDS writes.
// Block: 8 waves, 2 b's, 1 block/CU (grid 256):
//   wv0,1 = chain(b0,b1); wv2,3 = ctl(b0); wv4,5 = ctl(b1); wv6,7 = flush(b0,b1).
// LDS: out 2bb x 2buf x 64 x 25 f4 = 102.4KB; A,B ctl 2 x 24KB = 48KB; 148KB total.
// Parity audit (chunk c): chain R A/B[c&1], ctl W A/B[(c+1)&1], chain W out[c&1],
// flush R out[(c-1)&1] -- all disjoint.

#define N_B 512
#define N_L 64
#define N_H 80
#define DT_F 0.1f
#define PITCH_F4 25       // 24 used + 1 pad
#define SPC 8
#define NCH 10
#define INV2PI 0.15915494309189535f

__device__ __forceinline__ float fast_rcp(float x) { return __builtin_amdgcn_rcpf(x); }

__device__ __forceinline__ float fast_tanh(float x) {
    const float e2 = __expf(2.0f * x);
    return (e2 - 1.0f) * fast_rcp(e2 + 1.0f);
}

__device__ __forceinline__ float fast_sigmoid(float x) {
    return fast_rcp(1.0f + __expf(-x));
}

__device__ __forceinline__ float fast_atan_small(float z) {
    // |z| <= 0.42; odd Taylor through z^9, max err ~1e-5.
    const float z2 = z * z;
    float p = 1.0f / 9.0f;
    p = fmaf(p, z2, -1.0f / 7.0f);
    p = fmaf(p, z2, 1.0f / 5.0f);
    p = fmaf(p, z2, -1.0f / 3.0f);
    p = fmaf(p, z2, 1.0f);
    return z * p;
}

__device__ __forceinline__ float fast_tan_075(float x) {
    // tan(x) on |x|<=0.75, odd Taylor through x^13; max err ~3e-5 at edge.
    const float x2 = x * x;
    float p = 0.0035916f;
    p = fmaf(p, x2, 0.0088632f);
    p = fmaf(p, x2, 0.0218695f);
    p = fmaf(p, x2, 0.0539683f);
    p = fmaf(p, x2, 0.1333333f);
    p = fmaf(p, x2, 0.3333333f);
    return fmaf(p * x2, x, x);
}

__global__ __launch_bounds__(512) void degraded_bicycle_rollout_kernel(
    const float* __restrict__ x0,        // [512,12]
    const float* __restrict__ controls,  // [512,64,80,3]
    const float* __restrict__ deg,       // [512,5]
    float* __restrict__ out)             // [512,64,81,12]
{
    __shared__ float4 outb[2][2][N_L * PITCH_F4];  // [bb][buf] out staging
    __shared__ float  Abuf[2][2][512 * 3];         // tan_d, beta, acc  (e=s*64+l)
    __shared__ float  Bbuf[2][2][512 * 3];         // delta, fb, fx

    const int lane = threadIdx.x & 63;
    const int wv   = threadIdx.x >> 6;   // 0..7

    const int role = (wv < 2) ? 0 : (wv < 6) ? 1 : 2;   // 0=chain,1=ctl,2=flush
    const int bb   = (role == 0) ? wv : (role == 1) ? ((wv - 2) >> 1) : (wv - 6);
    const int b    = blockIdx.x * 2 + bb;
    const size_t out_b = (size_t)b * 62208;

#define FLUSH_CHUNK(BB, FBUF, FC)                                                 \
    {                                                                             \
        const size_t obase = out_b + 12 + (size_t)(FC) * (SPC * 12);              \
        _Pragma("unroll")                                                         \
        for (int i = 0; i < 24; ++i) {                                            \
            const unsigned flat = i * 64 + lane;                                  \
            const unsigned l = flat / 24u;                                        \
            const unsigned q = flat - l * 24u;                                    \
            const float4 v = outb[BB][FBUF][l * PITCH_F4 + q];                    \
            *reinterpret_cast<float4*>(out + obase + (size_t)l * 972 + q * 4) = v;\
        }                                                                         \
    }

    // ctl persona: compute make_ctl for chunk CC into parity PAR.
#define CTL_CHUNK(PT, BB, PAR, CC)                                                \
    {                                                                             \
        const float* dgc = deg + (blockIdx.x * 2 + (BB)) * 5;                     \
        const float steer_scale    = fmaxf(dgc[0], 0.05f);                        \
        const float brake_scale    = fmaxf(dgc[1], 0.05f);                        \
        const float throttle_scale = fmaxf(dgc[2], 0.05f);                        \
        const float friction       = fmaxf(dgc[4], 0.1f);                         \
        const float neg_brake_lim  = -7.5f * friction;                            \
        _Pragma("unroll")                                                         \
        for (int i = 0; i < 4; ++i) {                                             \
            const int t = i * 128 + (PT);        /* 0..511 */                     \
            const int l = t >> 3;                                                 \
            const int s = t & 7;                                                  \
            const size_t gidx = ((size_t)((blockIdx.x * 2 + (BB)) * 64 + l) * 80  \
                                 + (CC) * 8 + s) * 3;                             \
            const float u0 = controls[gidx + 0];                                  \
            const float u1 = controls[gidx + 1];                                  \
            const float u2 = controls[gidx + 2];                                  \
            const float delta = steer_scale * fast_tanh(u0);                      \
            const float fb = brake_scale    * fast_sigmoid(u1);                   \
            const float fx = throttle_scale * fast_sigmoid(u2);                   \
            const float dc = fminf(fmaxf(delta, -0.75f), 0.75f);                  \
            const float tan_d = fast_tan_075(dc);                                 \
            const float beta = fminf(fmaxf(fast_atan_small(0.45f * tan_d), -0.65f), 0.65f); \
            const float acc = fminf(fmaxf(2.8f * fx - 6.5f * fb, neg_brake_lim), 3.0f); \
            const int e3 = (s * 64 + l) * 3;                                      \
            Abuf[BB][PAR][e3 + 0] = tan_d;                                        \
            Abuf[BB][PAR][e3 + 1] = beta;                                         \
            Abuf[BB][PAR][e3 + 2] = acc;                                          \
            Bbuf[BB][PAR][e3 + 0] = delta;                                        \
            Bbuf[BB][PAR][e3 + 1] = fb;                                           \
            Bbuf[BB][PAR][e3 + 2] = fx;                                           \
        }                                                                         \
    }

    if (role == 0) {
        // ================= chain persona =================
        const float* dg = deg + b * 5;
        const float friction = fmaxf(dg[4], 0.1f);
        const float yaw_num = friction * 9.81f;
        const float inv_wheelbase = 1.0f / 2.8f;

        const float4* x0v = reinterpret_cast<const float4*>(x0 + b * 12);
        const float4 xi0 = x0v[0];
        const float4 xi1 = x0v[1];

        float px  = xi0.x;
        float py  = xi0.y;
        float psi = xi0.z;
        float vxp = xi0.w;
        float vyp = xi1.x;
        float s = __builtin_amdgcn_sqrtf(fmaf(vxp, vxp, fmaf(vyp, vyp, 1e-6f)));

        __syncthreads();   // B0: ctl chunk 0 staged

        for (int c = 0; c < NCH; ++c) {
            const int par = c & 1;
            float4* lrow = &outb[bb][par][lane * PITCH_F4];
            const float* Ab = &Abuf[bb][par][lane * 3];
            const float* Bb = &Bbuf[bb][par][lane * 3];

            #pragma unroll
            for (int st = 0; st < SPC; ++st) {
                const float tan_d = Ab[st * 192 + 0];
                const float beta  = Ab[st * 192 + 1];
                const float acc   = Ab[st * 192 + 2];
                const float delta = Bb[st * 192 + 0];
                const float fb    = Bb[st * 192 + 1];
                const float fx    = Bb[st * 192 + 2];

                const float s2 = fmaxf(fmaf(acc, DT_F, s), 0.0f);
                const float raw_yaw = s2 * inv_wheelbase * tan_d;
                const float yaw_lim = fmaxf(yaw_num * fast_rcp(fmaxf(s2, 2.0f)), 0.15f);
                const float yaw_rate = fminf(fmaxf(raw_yaw, -1.0f), 1.0f) * yaw_lim;
                const float psi2 = fmaf(yaw_rate, DT_F, psi);
                const float ang = (psi2 + beta) * INV2PI;
                const float sn = __builtin_amdgcn_sinf(ang);
                const float cs = __builtin_amdgcn_cosf(ang);
                const float vx2 = s2 * cs;
                const float vy2 = s2 * sn;
                const float px2 = fmaf(vx2, DT_F, px);
                const float py2 = fmaf(vy2, DT_F, py);
                const float ax = (vx2 - vxp) * 10.0f;
                const float ay = (vy2 - vyp) * 10.0f;

                lrow[st * 3 + 0] = make_float4(px2, py2, psi2, vx2);
                lrow[st * 3 + 1] = make_float4(vy2, yaw_rate, ax, ay);
                lrow[st * 3 + 2] = make_float4(beta, delta, fb, fx);

                s = __builtin_amdgcn_sqrtf(fmaf(s2, s2, 1e-6f));
                px = px2; py = py2; psi = psi2; vxp = vx2; vyp = vy2;
            }
            __syncthreads();   // B(c+1)
        }
    } else if (role == 1) {
        // ================= ctl persona =================
        const int pt = ((wv - 2) & 1) * 64 + lane;   // 0..127 within bb pair
        CTL_CHUNK(pt, bb, 0, 0)
        __syncthreads();   // B0

        for (int c = 0; c < NCH; ++c) {
            if (c + 1 < NCH) CTL_CHUNK(pt, bb, (c + 1) & 1, c + 1)
            __syncthreads();
        }
    } else {
        // ================= flusher persona =================
        {   // h=0 rows for this bb (prologue)
            const float4* x0v = reinterpret_cast<const float4*>(x0 + b * 12);
            const float4 xq0 = x0v[0];
            const float4 xq1 = x0v[1];
            const float4 xq2 = x0v[2];
            #pragma unroll
            for (int i = 0; i < 3; ++i) {
                const unsigned flat = i * 64 + lane;
                const unsigned l = flat / 3u;
                const unsigned q = flat - l * 3u;
                const float4 v = (q == 0) ? xq0 : (q == 1) ? xq1 : xq2;
                *reinterpret_cast<float4*>(out + out_b + (size_t)l * 972 + q * 4) = v;
            }
        }
        __syncthreads();   // B0

        for (int c = 0; c < NCH; ++c) {
            if (c > 0) FLUSH_CHUNK(bb, (c - 1) & 1, c - 1)
            __syncthreads();
        }
        FLUSH_CHUNK(bb, (NCH - 1) & 1, NCH - 1)
    }
#undef FLUSH_CHUNK
#undef CTL_CHUNK
}

extern "C" void kernel_launch(void* const* d_in, const int* in_sizes, int n_in,
                              void* d_out, int out_size, void* d_ws, size_t ws_size,
                              hipStream_t stream) {
    (void)in_sizes; (void)n_in; (void)d_ws; (void)ws_size; (void)out_size;
    const float* x0       = (const float*)d_in[0];
    const float* controls = (const float*)d_in[1];
    const float* deg      = (const float*)d_in[2];
    float* out            = (float*)d_out;

    dim3 grid(N_B / 2), block(512);           // 256 blocks (1/CU) x 8 waves
    hipLaunchKernelGGL(degraded_bicycle_rollout_kernel, grid, block, 0, stream,
                       x0, controls, deg, out);
}